// Round 3
// baseline (339.582 us; speedup 1.0000x reference)
//
#include <hip/hip_runtime.h>
#include <hip/hip_bf16.h>
#include <stdint.h>

// Problem constants
#define B_   512
#define T_   87
#define C_   512
#define H_   8
#define D_   64
#define BT_  44544        // B_*T_
#define BH_  4096         // B_*H_

typedef __attribute__((ext_vector_type(4))) float f32x4;
typedef __attribute__((ext_vector_type(8))) __bf16 bf16x8;
typedef __attribute__((ext_vector_type(4))) unsigned short u16x4;

__device__ __forceinline__ void gl_lds16(const void* g, void* l) {
  __builtin_amdgcn_global_load_lds(
      (const __attribute__((address_space(1))) unsigned int*)g,
      (__attribute__((address_space(3))) unsigned int*)l, 16, 0, 0);
}

template<int N>
__device__ __forceinline__ void waitv() {
  asm volatile("s_waitcnt vmcnt(%0)" :: "i"(N) : "memory");
}

__device__ __forceinline__ int mod29(int x) {
  return x < 29 ? x : (x < 58 ? x - 29 : x - 58);
}

// ---------------- converts ----------------

__global__ void convert_x_kernel(const float* __restrict__ x,
                                 __hip_bfloat16* __restrict__ xb, int n4) {
  int stride = gridDim.x * blockDim.x;
  for (int i = blockIdx.x * blockDim.x + threadIdx.x; i < n4; i += stride) {
    f32x4 v = ((const f32x4*)x)[i];
    u16x4 o;
    o.x = __builtin_bit_cast(unsigned short, __float2bfloat16(v.x));
    o.y = __builtin_bit_cast(unsigned short, __float2bfloat16(v.y));
    o.z = __builtin_bit_cast(unsigned short, __float2bfloat16(v.z));
    o.w = __builtin_bit_cast(unsigned short, __float2bfloat16(v.w));
    ((u16x4*)xb)[i] = o;
  }
}

__global__ void convert_w_kernel(const float* __restrict__ Wq, const float* __restrict__ Wk,
                                 const float* __restrict__ Wv, const float* __restrict__ Wp,
                                 const float* __restrict__ bq, const float* __restrict__ bk,
                                 const float* __restrict__ bv,
                                 __hip_bfloat16* __restrict__ wqkv,
                                 __hip_bfloat16* __restrict__ wp,
                                 float* __restrict__ biasc) {
  const int NW = 262144;                 // 512*512
  const int total = 3 * NW + NW + 1536;
  int stride = gridDim.x * blockDim.x;
  for (int i = blockIdx.x * blockDim.x + threadIdx.x; i < total; i += stride) {
    if (i < 3 * NW) {
      float v = (i < NW) ? Wq[i] : (i < 2 * NW ? Wk[i - NW] : Wv[i - 2 * NW]);
      wqkv[i] = __float2bfloat16(v);
    } else if (i < 4 * NW) {
      wp[i - 3 * NW] = __float2bfloat16(Wp[i - 3 * NW]);
    } else {
      int j = i - 4 * NW;
      biasc[j] = (j < 512) ? bq[j] : (j < 1024 ? bk[j - 512] : bv[j - 1024]);
    }
  }
}

// zero the pad rows (t = 87..95) of q/k and pad cols of vt
__global__ void zero_pads_kernel(__hip_bfloat16* __restrict__ q_ws,
                                 __hip_bfloat16* __restrict__ k_ws,
                                 __hip_bfloat16* __restrict__ vt_ws) {
  const int per = BH_ * 576;  // 9*64 pad elems per (b,h)
  int stride = gridDim.x * blockDim.x;
  __hip_bfloat16 z = __float2bfloat16(0.f);
  for (int i = blockIdx.x * blockDim.x + threadIdx.x; i < 3 * per; i += stride) {
    if (i < per) {
      int bh = i / 576, rem = i - (i / 576) * 576;
      q_ws[(size_t)bh * 6144 + 5568 + rem] = z;
    } else if (i < 2 * per) {
      int j = i - per;
      int bh = j / 576, rem = j - (j / 576) * 576;
      k_ws[(size_t)bh * 6144 + 5568 + rem] = z;
    } else {
      int j = i - 2 * per;
      int bh = j / 576, rem = j - (j / 576) * 576;
      int d = rem / 9, o = rem - d * 9;
      vt_ws[(size_t)bh * 6144 + d * 96 + 87 + o] = z;
    }
  }
}

// ---------------- shared GEMM building blocks ----------------
// LDS tile rows x 64 bf16 (128B rows), linear dest, XOR-swizzled content:
// LDS 16B-slot s of row r holds global slot s^(r&7) (m173 pre-swizzled source).
template<int ROWS, int NW>
__device__ __forceinline__ void stage_tile(const char* g, int kbyte,
                                           char* lbuf, int wave, int lane) {
  const int colsw = ((lane & 7) ^ (lane >> 3)) * 16;
  const int rl = lane >> 3;
#pragma unroll
  for (int j = 0; j < ROWS / (NW * 8); ++j) {
    int rbase = j * NW * 8 + wave * 8;                 // wave-uniform
    const char* src = g + (size_t)(rbase + rl) * 1024 + kbyte + colsw;
    gl_lds16(src, lbuf + rbase * 128);
  }
}

// one BK=64 K-tile: acc[FM][FN] += A[wbM..][k] * B[wbN..][k]^T
template<int FM, int FN>
__device__ __forceinline__ void compute_tile(const char* Ab, const char* Bb,
                                             int wbM, int wbN, int r16, int r4,
                                             f32x4 acc[FM][FN]) {
  const int cxor = (r16 & 7) << 4;
  bf16x8 bf[FN][2];
#pragma unroll
  for (int fn = 0; fn < FN; ++fn) {
    int row = wbN + fn * 16 + r16;
#pragma unroll
    for (int kk = 0; kk < 2; ++kk)
      bf[fn][kk] = *(const bf16x8*)(Bb + row * 128 + ((kk * 64 + r4 * 16) ^ cxor));
  }
#pragma unroll
  for (int fm = 0; fm < FM; ++fm) {
    int row = wbM + fm * 16 + r16;
    bf16x8 a0 = *(const bf16x8*)(Ab + row * 128 + ((r4 * 16) ^ cxor));
    bf16x8 a1 = *(const bf16x8*)(Ab + row * 128 + ((64 + r4 * 16) ^ cxor));
#pragma unroll
    for (int fn = 0; fn < FN; ++fn) {
      acc[fm][fn] = __builtin_amdgcn_mfma_f32_16x16x32_bf16(a0, bf[fn][0], acc[fm][fn], 0, 0, 0);
      acc[fm][fn] = __builtin_amdgcn_mfma_f32_16x16x32_bf16(a1, bf[fn][1], acc[fm][fn], 0, 0, 0);
    }
  }
}

// ---------------- 3-buffer counted-vmcnt GEMM core ----------------
// BM=128 fixed, 8 waves (2M x 4N), BK=64, K=512 (8 K-tiles), depth-2 prefetch.
// EPI 0: qkv scatter (o0=q,o1=k,o2=vt, bias=biasc). EPI 1: proj fp32 (o0=out, bias=bp).
template<int BN, int NTOT, int EPI>
__global__ __launch_bounds__(512, 2) void gemm3_kernel(
    const __hip_bfloat16* __restrict__ A, const __hip_bfloat16* __restrict__ Bt,
    const float* __restrict__ bias,
    void* __restrict__ o0, void* __restrict__ o1, void* __restrict__ o2) {
  constexpr int FN = BN / 64;            // frags per wave in N (wave covers BN/4)
  constexpr int LT = 2 + BN / 64;        // gl_lds loads per thread per K-tile
  constexpr int ABYTES = 128 * 128;      // 16KB
  constexpr int BUFB = ABYTES + BN * 128;
  __shared__ __align__(16) char smem[3 * BUFB];

  int tid = threadIdx.x, lane = tid & 63, wave = tid >> 6;
  int r16 = lane & 15, r4 = lane >> 4;

  // bijective XCD swizzle; grid divisible by 8 by construction
  int nwg = gridDim.x;
  int wg = (blockIdx.x & 7) * (nwg >> 3) + (blockIdx.x >> 3);
  constexpr int NT = NTOT / BN;
  int tileM = (wg / NT) * 128, tileN = (wg % NT) * BN;

  int wr = wave >> 2, wc = wave & 3;     // per-wave 64 x (BN/4)

  f32x4 acc[4][FN] = {};

  const char* Ag = (const char*)A + (size_t)tileM * 1024;
  const char* Bg = (const char*)Bt + (size_t)tileN * 1024;

  // prologue: stage K-tiles 0,1 into buffers 0,1
  stage_tile<128, 8>(Ag, 0, smem, wave, lane);
  stage_tile<BN, 8>(Bg, 0, smem + ABYTES, wave, lane);
  stage_tile<128, 8>(Ag, 128, smem + BUFB, wave, lane);
  stage_tile<BN, 8>(Bg, 128, smem + BUFB + ABYTES, wave, lane);

#pragma unroll
  for (int kt = 0; kt < 8; ++kt) {
    if (kt < 6) {  // stage tile kt+2 into ring buffer (kt+2)%3
      char* nb = smem + ((kt + 2) % 3) * BUFB;
      stage_tile<128, 8>(Ag, (kt + 2) * 128, nb, wave, lane);
      stage_tile<BN, 8>(Bg, (kt + 2) * 128, nb + ABYTES, wave, lane);
    }
    // counted wait: tile kt is the oldest outstanding group (in-order retire)
    if (kt < 6)      waitv<2 * LT>();
    else if (kt == 6) waitv<LT>();
    else              waitv<0>();
    __builtin_amdgcn_sched_barrier(0);
    __builtin_amdgcn_s_barrier();
    __builtin_amdgcn_sched_barrier(0);
    {
      const char* cb = smem + (kt % 3) * BUFB;
      __builtin_amdgcn_s_setprio(1);
      compute_tile<4, FN>(cb, cb + ABYTES, wr * 64, wc * (16 * FN), r16, r4, acc);
      __builtin_amdgcn_s_setprio(0);
    }
    __builtin_amdgcn_sched_barrier(0);
    __builtin_amdgcn_s_barrier();   // compute(kt) done before stage overwrites buf
    __builtin_amdgcn_sched_barrier(0);
  }

  // epilogue: C/D layout col=lane&15, row=(lane>>4)*4+reg [m89-verified]
#pragma unroll
  for (int fm = 0; fm < 4; ++fm) {
    int gmb = tileM + wr * 64 + fm * 16 + r4 * 4;
#pragma unroll
    for (int fn = 0; fn < FN; ++fn) {
      int gn = tileN + wc * (16 * FN) + fn * 16 + r16;
      float bv = bias[gn];
      if constexpr (EPI == 0) {
        int sel = gn >> 9;          // 0=q, 1=k, 2=v
        int n2 = gn & 511;
        int hh = n2 >> 6, dd = n2 & 63;
#pragma unroll
        for (int rr = 0; rr < 4; ++rr) {
          int gm = gmb + rr;
          int bb = gm / 87, tt = gm - bb * 87;
          __hip_bfloat16 hv = __float2bfloat16(acc[fm][fn][rr] + bv);
          if (sel == 0)
            ((__hip_bfloat16*)o0)[((size_t)(bb * 8 + hh) * 96 + tt) * 64 + dd] = hv;
          else if (sel == 1)
            ((__hip_bfloat16*)o1)[((size_t)(bb * 8 + hh) * 96 + tt) * 64 + dd] = hv;
          else
            ((__hip_bfloat16*)o2)[((size_t)(bb * 8 + hh) * 64 + dd) * 96 + tt] = hv;
        }
      } else {
#pragma unroll
        for (int rr = 0; rr < 4; ++rr)
          ((float*)o0)[(size_t)(gmb + rr) * 512 + gn] = acc[fm][fn][rr] + bv;
      }
    }
  }
}

// ---------------- attention per (b,h) (unchanged this round) ----------------
__global__ __launch_bounds__(256) void attn_kernel(
    const __hip_bfloat16* __restrict__ q_ws, const __hip_bfloat16* __restrict__ k_ws,
    const __hip_bfloat16* __restrict__ vt_ws, __hip_bfloat16* __restrict__ y_ws) {
  __shared__ __align__(16) char smem[73728];
  __hip_bfloat16* Qs  = (__hip_bfloat16*)smem;             // [96][64] 12KB
  __hip_bfloat16* Ks  = (__hip_bfloat16*)(smem + 12288);   // [96][64] 12KB
  __hip_bfloat16* Vts = (__hip_bfloat16*)(smem + 24576);   // [64][96] 12KB
  float* Sb           = (float*)(smem + 36864);            // [96][96] fp32 36KB
  __hip_bfloat16* Pb  = (__hip_bfloat16*)smem;             // [96][96] aliases Qs+Ks

  int tid = threadIdx.x, lane = tid & 63, wave = tid >> 6;
  int bh = blockIdx.x, b = bh >> 3, h = bh & 7;
  int r16 = lane & 15, r4 = lane >> 4;

  {
    const bf16x8* gq = (const bf16x8*)(q_ws + (size_t)bh * 6144);
    const bf16x8* gk = (const bf16x8*)(k_ws + (size_t)bh * 6144);
    const bf16x8* gv = (const bf16x8*)(vt_ws + (size_t)bh * 6144);
    bf16x8* lq = (bf16x8*)Qs; bf16x8* lk = (bf16x8*)Ks; bf16x8* lv = (bf16x8*)Vts;
    for (int i = tid; i < 768; i += 256) { lq[i] = gq[i]; lk[i] = gk[i]; lv[i] = gv[i]; }
  }
  __syncthreads();

  // S = Q K^T : 6x6 16-tiles, K=64
  for (int p = 0; p < 9; ++p) {
    int pair = wave + p * 4;
    int mt = pair / 6, nt = pair - mt * 6;
    f32x4 acc = {0.f, 0.f, 0.f, 0.f};
#pragma unroll
    for (int kk = 0; kk < 2; ++kk) {
      bf16x8 a  = *(const bf16x8*)(Qs + (mt * 16 + r16) * 64 + kk * 32 + r4 * 8);
      bf16x8 bb = *(const bf16x8*)(Ks + (nt * 16 + r16) * 64 + kk * 32 + r4 * 8);
      acc = __builtin_amdgcn_mfma_f32_16x16x32_bf16(a, bb, acc, 0, 0, 0);
    }
    int row0 = mt * 16 + r4 * 4, col = nt * 16 + r16;
#pragma unroll
    for (int r = 0; r < 4; ++r) Sb[(row0 + r) * 96 + col] = acc[r];
  }
  __syncthreads();

  // masked softmax, one 32-lane group per row
  int group = tid >> 5, glane = tid & 31;
  for (int r = group; r < 96; r += 8) {
    if (r < 87) {
      int lr = mod29(r);
      float sv[3]; bool al[3];
      float mx = -__builtin_inff();
#pragma unroll
      for (int q = 0; q < 3; ++q) {
        int j = glane + q * 32;
        int lj = mod29(j);
        al[q] = (j < 87) && (lj <= lr) && (lj >= lr - 21);
        sv[q] = al[q] ? Sb[r * 96 + j] * 0.125f : -__builtin_inff();
        mx = fmaxf(mx, sv[q]);
      }
#pragma unroll
      for (int o = 16; o >= 1; o >>= 1) mx = fmaxf(mx, __shfl_xor(mx, o, 32));
      float e[3], sum = 0.f;
#pragma unroll
      for (int q = 0; q < 3; ++q) { e[q] = al[q] ? __expf(sv[q] - mx) : 0.f; sum += e[q]; }
#pragma unroll
      for (int o = 16; o >= 1; o >>= 1) sum += __shfl_xor(sum, o, 32);
      float inv = 1.f / sum;
#pragma unroll
      for (int q = 0; q < 3; ++q)
        Pb[r * 96 + glane + q * 32] = __float2bfloat16(e[q] * inv);
    } else {
#pragma unroll
      for (int q = 0; q < 3; ++q) Pb[r * 96 + glane + q * 32] = __float2bfloat16(0.f);
    }
  }
  __syncthreads();

  // Y = P V : A=P [96][96], Bt=Vt [64][96], 6x4 16-tiles, K=96
  for (int p = 0; p < 6; ++p) {
    int pair = wave + p * 4;
    int mt = pair >> 2, nt = pair & 3;
    f32x4 acc = {0.f, 0.f, 0.f, 0.f};
#pragma unroll
    for (int kk = 0; kk < 3; ++kk) {
      bf16x8 a  = *(const bf16x8*)(Pb + (mt * 16 + r16) * 96 + kk * 32 + r4 * 8);
      bf16x8 bb = *(const bf16x8*)(Vts + (nt * 16 + r16) * 96 + kk * 32 + r4 * 8);
      acc = __builtin_amdgcn_mfma_f32_16x16x32_bf16(a, bb, acc, 0, 0, 0);
    }
    int t0 = mt * 16 + r4 * 4, d = nt * 16 + r16;
#pragma unroll
    for (int r = 0; r < 4; ++r) {
      int t = t0 + r;
      if (t < 87)
        y_ws[((size_t)b * 87 + t) * 512 + h * 64 + d] = __float2bfloat16(acc[r]);
    }
  }
}

// ---------------- launch ----------------
extern "C" void kernel_launch(void* const* d_in, const int* in_sizes, int n_in,
                              void* d_out, int out_size, void* d_ws, size_t ws_size,
                              hipStream_t stream) {
  const float* x  = (const float*)d_in[0];
  const float* Wq = (const float*)d_in[1];
  const float* bq = (const float*)d_in[2];
  const float* Wk = (const float*)d_in[3];
  const float* bk = (const float*)d_in[4];
  const float* Wv = (const float*)d_in[5];
  const float* bv = (const float*)d_in[6];
  const float* Wp = (const float*)d_in[7];
  const float* bp = (const float*)d_in[8];
  float* out = (float*)d_out;

  char* ws = (char*)d_ws;
  size_t off = 0;
  __hip_bfloat16* xb    = (__hip_bfloat16*)(ws + off); off += (size_t)BT_ * 512 * 2;
  __hip_bfloat16* wqkv  = (__hip_bfloat16*)(ws + off); off += 1536 * 512 * 2;
  __hip_bfloat16* wp    = (__hip_bfloat16*)(ws + off); off += 512 * 512 * 2;
  float*          biasc = (float*)(ws + off);          off += 8192;
  __hip_bfloat16* q_ws  = (__hip_bfloat16*)(ws + off); off += (size_t)BH_ * 6144 * 2;
  __hip_bfloat16* k_ws  = (__hip_bfloat16*)(ws + off); off += (size_t)BH_ * 6144 * 2;
  __hip_bfloat16* vt_ws = (__hip_bfloat16*)(ws + off); off += (size_t)BH_ * 6144 * 2;
  __hip_bfloat16* yb = xb;  // alias: xb fully consumed by gemm_qkv before attn writes y

  if (ws_size < off) return;

  convert_x_kernel<<<2048, 256, 0, stream>>>(x, xb, BT_ * 512 / 4);
  convert_w_kernel<<<1024, 256, 0, stream>>>(Wq, Wk, Wv, Wp, bq, bk, bv, wqkv, wp, biasc);
  zero_pads_kernel<<<2048, 256, 0, stream>>>(q_ws, k_ws, vt_ws);
  // qkv: BM=128, BN=192, N-tiles=8, M-tiles=348 -> 2784 blocks (divisible by 8)
  gemm3_kernel<192, 1536, 0><<<2784, 512, 0, stream>>>(xb, wqkv, biasc, q_ws, k_ws, vt_ws);
  attn_kernel<<<BH_, 256, 0, stream>>>(q_ws, k_ws, vt_ws, yb);
  // proj: BM=128, BN=128, N-tiles=4, M-tiles=348 -> 1392 blocks (divisible by 8)
  gemm3_kernel<128, 512, 1><<<1392, 512, 0, stream>>>(yb, wp, bp, out, nullptr, nullptr);
}

// Round 5
// 338.321 us; speedup vs baseline: 1.0037x; 1.0037x over previous
//
#include <hip/hip_runtime.h>
#include <hip/hip_bf16.h>
#include <stdint.h>

// Problem constants
#define B_   512
#define T_   87
#define C_   512
#define H_   8
#define D_   64
#define BT_  44544        // B_*T_
#define BH_  4096         // B_*H_

typedef __attribute__((ext_vector_type(4))) float f32x4;
typedef __attribute__((ext_vector_type(8))) __bf16 bf16x8;
typedef __attribute__((ext_vector_type(4))) unsigned short u16x4;

__device__ __forceinline__ void gl_lds16(const void* g, void* l) {
  __builtin_amdgcn_global_load_lds(
      (const __attribute__((address_space(1))) unsigned int*)g,
      (__attribute__((address_space(3))) unsigned int*)l, 16, 0, 0);
}

template<int N>
__device__ __forceinline__ void waitv() {
  asm volatile("s_waitcnt vmcnt(%0)" :: "i"(N) : "memory");
}

__device__ __forceinline__ int mod29(int x) {
  return x < 29 ? x : (x < 58 ? x - 29 : x - 58);
}

// ---------------- converts ----------------

__global__ void convert_x_kernel(const float* __restrict__ x,
                                 __hip_bfloat16* __restrict__ xb, int n4) {
  int stride = gridDim.x * blockDim.x;
  for (int i = blockIdx.x * blockDim.x + threadIdx.x; i < n4; i += stride) {
    f32x4 v = ((const f32x4*)x)[i];
    u16x4 o;
    o.x = __builtin_bit_cast(unsigned short, __float2bfloat16(v.x));
    o.y = __builtin_bit_cast(unsigned short, __float2bfloat16(v.y));
    o.z = __builtin_bit_cast(unsigned short, __float2bfloat16(v.z));
    o.w = __builtin_bit_cast(unsigned short, __float2bfloat16(v.w));
    ((u16x4*)xb)[i] = o;
  }
}

__global__ void convert_w_kernel(const float* __restrict__ Wq, const float* __restrict__ Wk,
                                 const float* __restrict__ Wv, const float* __restrict__ Wp,
                                 const float* __restrict__ bq, const float* __restrict__ bk,
                                 const float* __restrict__ bv,
                                 __hip_bfloat16* __restrict__ wqkv,
                                 __hip_bfloat16* __restrict__ wp,
                                 float* __restrict__ biasc) {
  const int NW = 262144;                 // 512*512
  const int total = 3 * NW + NW + 1536;
  int stride = gridDim.x * blockDim.x;
  for (int i = blockIdx.x * blockDim.x + threadIdx.x; i < total; i += stride) {
    if (i < 3 * NW) {
      float v = (i < NW) ? Wq[i] : (i < 2 * NW ? Wk[i - NW] : Wv[i - 2 * NW]);
      wqkv[i] = __float2bfloat16(v);
    } else if (i < 4 * NW) {
      wp[i - 3 * NW] = __float2bfloat16(Wp[i - 3 * NW]);
    } else {
      int j = i - 4 * NW;
      biasc[j] = (j < 512) ? bq[j] : (j < 1024 ? bk[j - 512] : bv[j - 1024]);
    }
  }
}

// zero the pad rows (t = 87..95) of q/k and pad cols of vt
__global__ void zero_pads_kernel(__hip_bfloat16* __restrict__ q_ws,
                                 __hip_bfloat16* __restrict__ k_ws,
                                 __hip_bfloat16* __restrict__ vt_ws) {
  const int per = BH_ * 576;  // 9*64 pad elems per (b,h)
  int stride = gridDim.x * blockDim.x;
  __hip_bfloat16 z = __float2bfloat16(0.f);
  for (int i = blockIdx.x * blockDim.x + threadIdx.x; i < 3 * per; i += stride) {
    if (i < per) {
      int bh = i / 576, rem = i - (i / 576) * 576;
      q_ws[(size_t)bh * 6144 + 5568 + rem] = z;
    } else if (i < 2 * per) {
      int j = i - per;
      int bh = j / 576, rem = j - (j / 576) * 576;
      k_ws[(size_t)bh * 6144 + 5568 + rem] = z;
    } else {
      int j = i - 2 * per;
      int bh = j / 576, rem = j - (j / 576) * 576;
      int d = rem / 9, o = rem - d * 9;
      vt_ws[(size_t)bh * 6144 + d * 96 + 87 + o] = z;
    }
  }
}

// ---------------- BK=32 fine-grained GEMM core ----------------
// LDS slot = A panel (BM rows x 64B) + B panel (256 rows x 64B). Rows are 64B
// (4 x 16B chunks). Swizzle: LDS chunk s of row r holds global chunk
// s ^ ((r>>1)&3)  -> ds_read 2-way bank aliasing only (free, m136).

// stage one panel (ROWS x 64B), ROWS/128 gl_lds per thread, 512 threads
template<int ROWS>
__device__ __forceinline__ void stage32(const char* g, int kbyte, char* dst,
                                        int wave, int lane) {
  int rl = lane >> 2, s = lane & 3;
#pragma unroll
  for (int j = 0; j < ROWS / 128; ++j) {
    int rbase = j * 128 + wave * 16;
    int row = rbase + rl;
    int colsw = ((s ^ ((row >> 1) & 3)) << 4);
    gl_lds16(g + (size_t)row * 1024 + kbyte + colsw, dst + rbase * 64);
  }
}

// one BK=32 K-tile: acc[FM][FN] += A[wbM..][k] * B[wbN..][k]^T
template<int FM, int FN>
__device__ __forceinline__ void compute32(const char* Ab, const char* Bb,
                                          int wbM, int wbN, int r16, int r4,
                                          f32x4 acc[FM][FN]) {
  bf16x8 bfr[FN];
#pragma unroll
  for (int fn = 0; fn < FN; ++fn) {
    int row = wbN + fn * 16 + r16;
    bfr[fn] = *(const bf16x8*)(Bb + row * 64 + ((r4 ^ ((row >> 1) & 3)) << 4));
  }
#pragma unroll
  for (int fm = 0; fm < FM; ++fm) {
    int row = wbM + fm * 16 + r16;
    bf16x8 a = *(const bf16x8*)(Ab + row * 64 + ((r4 ^ ((row >> 1) & 3)) << 4));
#pragma unroll
    for (int fn = 0; fn < FN; ++fn)
      acc[fm][fn] = __builtin_amdgcn_mfma_f32_16x16x32_bf16(a, bfr[fn], acc[fm][fn], 0, 0, 0);
  }
}

// BM x 256 tile, 8 waves (2M x 4N), BK=32, 16 K-tiles, 4-buffer ring, depth-3.
// EPI 0: qkv scatter (o0=q,o1=k,o2=vt). EPI 1: proj fp32 (o0=out).
template<int BM, int EPI>
__global__ __launch_bounds__(512, 2) void gemmf_kernel(
    const __hip_bfloat16* __restrict__ A, const __hip_bfloat16* __restrict__ Bt,
    const float* __restrict__ bias, int ntiles,
    void* __restrict__ o0, void* __restrict__ o1, void* __restrict__ o2) {
  constexpr int FM = BM / 32;               // wave covers BM/2 rows
  constexpr int LT = BM / 128 + 2;          // gl_lds per thread per K-tile (A+B) !
  constexpr int ABYTES = BM * 64;           // A panel bytes per slot
  constexpr int SLOT = ABYTES + 256 * 64;   // + B panel 16KB
  __shared__ __align__(16) char smem[4 * SLOT];

  int tid = threadIdx.x, lane = tid & 63, wave = tid >> 6;
  int r16 = lane & 15, r4 = lane >> 4;

  // bijective XCD swizzle (m204)
  int nwg = gridDim.x;
  int xcd = blockIdx.x & 7, idx = blockIdx.x >> 3;
  int q8 = nwg >> 3, r8 = nwg & 7;
  int wg = (xcd < r8 ? xcd * (q8 + 1) : r8 * (q8 + 1) + (xcd - r8) * q8) + idx;
  int tileM = (wg / ntiles) * BM, tileN = (wg % ntiles) * 256;

  int wr = wave >> 2, wc = wave & 3;        // per-wave (BM/2) x 64
  int wbM = wr * (BM / 2), wbN = wc * 64;

  f32x4 acc[FM][4] = {};

  const char* Ag = (const char*)A + (size_t)tileM * 1024;
  const char* Bg = (const char*)Bt + (size_t)tileN * 1024;

  // prologue: stage K-tiles 0,1,2 into slots 0,1,2  (3*LT outstanding)
#pragma unroll
  for (int t = 0; t < 3; ++t) {
    stage32<BM>(Ag, t * 64, smem + t * SLOT, wave, lane);
    stage32<256>(Bg, t * 64, smem + t * SLOT + ABYTES, wave, lane);
  }

  // steady loop: wait own tile-kt loads (leave tiles kt+1,kt+2 = 2*LT in
  // flight), barrier, prefetch kt+3, fine-grained ds_read+MFMA, barrier.
#pragma unroll
  for (int kt = 0; kt < 13; ++kt) {
    waitv<2 * LT>();
    __builtin_amdgcn_sched_barrier(0);
    __builtin_amdgcn_s_barrier();
    __builtin_amdgcn_sched_barrier(0);
    char* nb = smem + ((kt + 3) & 3) * SLOT;   // slot last read at step kt-1
    stage32<BM>(Ag, (kt + 3) * 64, nb, wave, lane);
    stage32<256>(Bg, (kt + 3) * 64, nb + ABYTES, wave, lane);
    const char* cb = smem + (kt & 3) * SLOT;
    __builtin_amdgcn_s_setprio(1);
    compute32<FM, 4>(cb, cb + ABYTES, wbM, wbN, r16, r4, acc);
    __builtin_amdgcn_s_setprio(0);
    __builtin_amdgcn_sched_barrier(0);
    __builtin_amdgcn_s_barrier();
    __builtin_amdgcn_sched_barrier(0);
  }
  // tail: kt = 13,14,15 (no staging; step down the counted wait)
  {
    waitv<2 * LT>();
    __builtin_amdgcn_s_barrier();
    const char* cb = smem + (13 & 3) * SLOT;
    __builtin_amdgcn_s_setprio(1);
    compute32<FM, 4>(cb, cb + ABYTES, wbM, wbN, r16, r4, acc);
    __builtin_amdgcn_s_setprio(0);
    __builtin_amdgcn_s_barrier();
  }
  {
    waitv<LT>();
    __builtin_amdgcn_s_barrier();
    const char* cb = smem + (14 & 3) * SLOT;
    __builtin_amdgcn_s_setprio(1);
    compute32<FM, 4>(cb, cb + ABYTES, wbM, wbN, r16, r4, acc);
    __builtin_amdgcn_s_setprio(0);
    __builtin_amdgcn_s_barrier();
  }
  {
    waitv<0>();
    __builtin_amdgcn_s_barrier();
    const char* cb = smem + (15 & 3) * SLOT;
    compute32<FM, 4>(cb, cb + ABYTES, wbM, wbN, r16, r4, acc);
  }

  // epilogue: C/D layout col=lane&15, row=(lane>>4)*4+reg [m89-verified]
#pragma unroll
  for (int fm = 0; fm < FM; ++fm) {
    int gmb = tileM + wbM + fm * 16 + r4 * 4;
#pragma unroll
    for (int fn = 0; fn < 4; ++fn) {
      int gn = tileN + wbN + fn * 16 + r16;
      float bv = bias[gn];
      if constexpr (EPI == 0) {
        int sel = gn >> 9;          // 0=q, 1=k, 2=v
        int n2 = gn & 511;
        int hh = n2 >> 6, dd = n2 & 63;
#pragma unroll
        for (int rr = 0; rr < 4; ++rr) {
          int gm = gmb + rr;
          int bb = gm / 87, tt = gm - bb * 87;
          __hip_bfloat16 hv = __float2bfloat16(acc[fm][fn][rr] + bv);
          if (sel == 0)
            ((__hip_bfloat16*)o0)[((size_t)(bb * 8 + hh) * 96 + tt) * 64 + dd] = hv;
          else if (sel == 1)
            ((__hip_bfloat16*)o1)[((size_t)(bb * 8 + hh) * 96 + tt) * 64 + dd] = hv;
          else
            ((__hip_bfloat16*)o2)[((size_t)(bb * 8 + hh) * 64 + dd) * 96 + tt] = hv;
        }
      } else {
#pragma unroll
        for (int rr = 0; rr < 4; ++rr)
          ((float*)o0)[(size_t)(gmb + rr) * 512 + gn] = acc[fm][fn][rr] + bv;
      }
    }
  }
}

// ---------------- attention per (b,h) (unchanged this round) ----------------
__global__ __launch_bounds__(256) void attn_kernel(
    const __hip_bfloat16* __restrict__ q_ws, const __hip_bfloat16* __restrict__ k_ws,
    const __hip_bfloat16* __restrict__ vt_ws, __hip_bfloat16* __restrict__ y_ws) {
  __shared__ __align__(16) char smem[73728];
  __hip_bfloat16* Qs  = (__hip_bfloat16*)smem;             // [96][64] 12KB
  __hip_bfloat16* Ks  = (__hip_bfloat16*)(smem + 12288);   // [96][64] 12KB
  __hip_bfloat16* Vts = (__hip_bfloat16*)(smem + 24576);   // [64][96] 12KB
  float* Sb           = (float*)(smem + 36864);            // [96][96] fp32 36KB
  __hip_bfloat16* Pb  = (__hip_bfloat16*)smem;             // [96][96] aliases Qs+Ks

  int tid = threadIdx.x, lane = tid & 63, wave = tid >> 6;
  int bh = blockIdx.x, b = bh >> 3, h = bh & 7;
  int r16 = lane & 15, r4 = lane >> 4;

  {
    const bf16x8* gq = (const bf16x8*)(q_ws + (size_t)bh * 6144);
    const bf16x8* gk = (const bf16x8*)(k_ws + (size_t)bh * 6144);
    const bf16x8* gv = (const bf16x8*)(vt_ws + (size_t)bh * 6144);
    bf16x8* lq = (bf16x8*)Qs; bf16x8* lk = (bf16x8*)Ks; bf16x8* lv = (bf16x8*)Vts;
    for (int i = tid; i < 768; i += 256) { lq[i] = gq[i]; lk[i] = gk[i]; lv[i] = gv[i]; }
  }
  __syncthreads();

  // S = Q K^T : 6x6 16-tiles, K=64
  for (int p = 0; p < 9; ++p) {
    int pair = wave + p * 4;
    int mt = pair / 6, nt = pair - mt * 6;
    f32x4 acc = {0.f, 0.f, 0.f, 0.f};
#pragma unroll
    for (int kk = 0; kk < 2; ++kk) {
      bf16x8 a  = *(const bf16x8*)(Qs + (mt * 16 + r16) * 64 + kk * 32 + r4 * 8);
      bf16x8 bb = *(const bf16x8*)(Ks + (nt * 16 + r16) * 64 + kk * 32 + r4 * 8);
      acc = __builtin_amdgcn_mfma_f32_16x16x32_bf16(a, bb, acc, 0, 0, 0);
    }
    int row0 = mt * 16 + r4 * 4, col = nt * 16 + r16;
#pragma unroll
    for (int r = 0; r < 4; ++r) Sb[(row0 + r) * 96 + col] = acc[r];
  }
  __syncthreads();

  // masked softmax, one 32-lane group per row
  int group = tid >> 5, glane = tid & 31;
  for (int r = group; r < 96; r += 8) {
    if (r < 87) {
      int lr = mod29(r);
      float sv[3]; bool al[3];
      float mx = -__builtin_inff();
#pragma unroll
      for (int q = 0; q < 3; ++q) {
        int j = glane + q * 32;
        int lj = mod29(j);
        al[q] = (j < 87) && (lj <= lr) && (lj >= lr - 21);
        sv[q] = al[q] ? Sb[r * 96 + j] * 0.125f : -__builtin_inff();
        mx = fmaxf(mx, sv[q]);
      }
#pragma unroll
      for (int o = 16; o >= 1; o >>= 1) mx = fmaxf(mx, __shfl_xor(mx, o, 32));
      float e[3], sum = 0.f;
#pragma unroll
      for (int q = 0; q < 3; ++q) { e[q] = al[q] ? __expf(sv[q] - mx) : 0.f; sum += e[q]; }
#pragma unroll
      for (int o = 16; o >= 1; o >>= 1) sum += __shfl_xor(sum, o, 32);
      float inv = 1.f / sum;
#pragma unroll
      for (int q = 0; q < 3; ++q)
        Pb[r * 96 + glane + q * 32] = __float2bfloat16(e[q] * inv);
    } else {
#pragma unroll
      for (int q = 0; q < 3; ++q) Pb[r * 96 + glane + q * 32] = __float2bfloat16(0.f);
    }
  }
  __syncthreads();

  // Y = P V : A=P [96][96], Bt=Vt [64][96], 6x4 16-tiles, K=96
  for (int p = 0; p < 6; ++p) {
    int pair = wave + p * 4;
    int mt = pair >> 2, nt = pair & 3;
    f32x4 acc = {0.f, 0.f, 0.f, 0.f};
#pragma unroll
    for (int kk = 0; kk < 3; ++kk) {
      bf16x8 a  = *(const bf16x8*)(Pb + (mt * 16 + r16) * 96 + kk * 32 + r4 * 8);
      bf16x8 bb = *(const bf16x8*)(Vts + (nt * 16 + r16) * 96 + kk * 32 + r4 * 8);
      acc = __builtin_amdgcn_mfma_f32_16x16x32_bf16(a, bb, acc, 0, 0, 0);
    }
    int t0 = mt * 16 + r4 * 4, d = nt * 16 + r16;
#pragma unroll
    for (int r = 0; r < 4; ++r) {
      int t = t0 + r;
      if (t < 87)
        y_ws[((size_t)b * 87 + t) * 512 + h * 64 + d] = __float2bfloat16(acc[r]);
    }
  }
}

// ---------------- launch ----------------
extern "C" void kernel_launch(void* const* d_in, const int* in_sizes, int n_in,
                              void* d_out, int out_size, void* d_ws, size_t ws_size,
                              hipStream_t stream) {
  const float* x  = (const float*)d_in[0];
  const float* Wq = (const float*)d_in[1];
  const float* bq = (const float*)d_in[2];
  const float* Wk = (const float*)d_in[3];
  const float* bk = (const float*)d_in[4];
  const float* Wv = (const float*)d_in[5];
  const float* bv = (const float*)d_in[6];
  const float* Wp = (const float*)d_in[7];
  const float* bp = (const float*)d_in[8];
  float* out = (float*)d_out;

  char* ws = (char*)d_ws;
  size_t off = 0;
  __hip_bfloat16* xb    = (__hip_bfloat16*)(ws + off); off += (size_t)BT_ * 512 * 2;
  __hip_bfloat16* wqkv  = (__hip_bfloat16*)(ws + off); off += 1536 * 512 * 2;
  __hip_bfloat16* wp    = (__hip_bfloat16*)(ws + off); off += 512 * 512 * 2;
  float*          biasc = (float*)(ws + off);          off += 8192;
  __hip_bfloat16* q_ws  = (__hip_bfloat16*)(ws + off); off += (size_t)BH_ * 6144 * 2;
  __hip_bfloat16* k_ws  = (__hip_bfloat16*)(ws + off); off += (size_t)BH_ * 6144 * 2;
  __hip_bfloat16* vt_ws = (__hip_bfloat16*)(ws + off); off += (size_t)BH_ * 6144 * 2;
  __hip_bfloat16* yb = xb;  // alias: xb fully consumed by gemm_qkv before attn writes y

  if (ws_size < off) return;

  convert_x_kernel<<<2048, 256, 0, stream>>>(x, xb, BT_ * 512 / 4);
  convert_w_kernel<<<1024, 256, 0, stream>>>(Wq, Wk, Wv, Wp, bq, bk, bv, wqkv, wp, biasc);
  zero_pads_kernel<<<2048, 256, 0, stream>>>(q_ws, k_ws, vt_ws);
  // qkv: 256x256 tiles -> 174 M-tiles x 6 N-tiles = 1044 blocks
  gemmf_kernel<256, 0><<<1044, 512, 0, stream>>>(xb, wqkv, biasc, 6, q_ws, k_ws, vt_ws);
  attn_kernel<<<BH_, 256, 0, stream>>>(q_ws, k_ws, vt_ws, yb);
  // proj: 128x256 tiles -> 348 M-tiles x 2 N-tiles = 696 blocks
  gemmf_kernel<128, 1><<<696, 512, 0, stream>>>(yb, wp, bp, 2, out, nullptr, nullptr);
}